// Round 2
// 506.221 us; speedup vs baseline: 1.1111x; 1.1111x over previous
//
#include <hip/hip_runtime.h>

namespace {
constexpr int kB  = 16;
constexpr int kS  = 512;
constexpr int kH  = 768;
constexpr int kNH = 12;
constexpr int kHD = 64;
constexpr int kM  = kB * kS;   // 8192
}

typedef __attribute__((ext_vector_type(8))) short  short8;   // bf16x8 frag (4 VGPRs)
typedef __attribute__((ext_vector_type(4))) float  f32x4;    // MFMA acc / NT stores
typedef __attribute__((ext_vector_type(4))) unsigned short us4;

__device__ __forceinline__ unsigned short f2bf(float x) {
    unsigned u = __float_as_uint(x);
    return (unsigned short)((u + 0x7FFFu + ((u >> 16) & 1u)) >> 16);   // RNE
}

__device__ __forceinline__ void load_lds16(const unsigned short* g, unsigned short* l) {
    __builtin_amdgcn_global_load_lds(
        (const __attribute__((address_space(1))) void*)g,
        (__attribute__((address_space(3))) void*)l,
        16, 0, 0);
}

// ---------------------------------------------------------------------------
// fp32 -> bf16 conversion (exact-sized launch; 4 elems/thr)
// ---------------------------------------------------------------------------
__global__ __launch_bounds__(256) void f32_to_bf16_kernel(
    const float* __restrict__ src, unsigned short* __restrict__ dst, int n4)
{
    int i = blockIdx.x * 256 + threadIdx.x;
    if (i >= n4) return;
    float4 v = reinterpret_cast<const float4*>(src)[i];
    us4 o;
    o.x = f2bf(v.x); o.y = f2bf(v.y); o.z = f2bf(v.z); o.w = f2bf(v.w);
    reinterpret_cast<us4*>(dst)[i] = o;
}

// ---------------------------------------------------------------------------
// QKV projection, bf16 MFMA (m97 structure): out[m][n] = sum_k h[m][k]W[n][k]+b
// 128x128 block tile, BK=32, 4 waves, per-wave 4x4 frags of 16x16x32_bf16.
// Output fp32, split-head layout [b,h,s,d].   (unchanged this round)
// ---------------------------------------------------------------------------
__global__ __launch_bounds__(256) void qkv_mfma_kernel(
    const unsigned short* __restrict__ hbf,
    const unsigned short* __restrict__ Wqb,
    const unsigned short* __restrict__ Wkb,
    const unsigned short* __restrict__ Wvb,
    const float* __restrict__ bq, const float* __restrict__ bk,
    const float* __restrict__ bv,
    float* __restrict__ qo, float* __restrict__ ko, float* __restrict__ vo)
{
    const int which = blockIdx.z;
    const unsigned short* W = (which == 0) ? Wqb : (which == 1) ? Wkb : Wvb;
    const float* bias       = (which == 0) ? bq  : (which == 1) ? bk  : bv;
    float* out              = (which == 0) ? qo  : (which == 1) ? ko  : vo;

    const int n0 = blockIdx.x * 128;
    const int m0 = blockIdx.y * 128;

    const int t    = threadIdx.x;
    const int lane = t & 63;
    const int w    = t >> 6;        // wave 0..3
    const int wm   = w >> 1;        // 0..1 (row half)
    const int wn   = w & 1;         // 0..1 (col half)

    __shared__ unsigned short As[128 * 32];   // [m][k], 64 B rows
    __shared__ unsigned short Bs[128 * 32];   // [n][k]

    f32x4 acc[4][4] = {};

    const int srow  = w * 32 + (lane >> 2);
    const int skoff = (lane & 3) * 8;
    const unsigned short* gA0 = hbf + (size_t)(m0 + srow) * kH + skoff;
    const unsigned short* gA1 = gA0 + (size_t)16 * kH;
    const unsigned short* gB0 = W   + (size_t)(n0 + srow) * kH + skoff;
    const unsigned short* gB1 = gB0 + (size_t)16 * kH;
    unsigned short* lA0 = &As[(w * 32) * 32];
    unsigned short* lA1 = &As[(w * 32 + 16) * 32];
    unsigned short* lB0 = &Bs[(w * 32) * 32];
    unsigned short* lB1 = &Bs[(w * 32 + 16) * 32];

    const int frow = lane & 15;     // frag row/col within 16
    const int fk   = (lane >> 4) * 8;

    for (int k0 = 0; k0 < kH; k0 += 32) {
        load_lds16(gA0 + k0, lA0);
        load_lds16(gA1 + k0, lA1);
        load_lds16(gB0 + k0, lB0);
        load_lds16(gB1 + k0, lB1);
        __syncthreads();            // drains vmcnt(0): LDS tiles ready

        short8 af[4], bf[4];
#pragma unroll
        for (int i = 0; i < 4; ++i)
            af[i] = *reinterpret_cast<const short8*>(
                &As[(wm * 64 + i * 16 + frow) * 32 + fk]);
#pragma unroll
        for (int j = 0; j < 4; ++j)
            bf[j] = *reinterpret_cast<const short8*>(
                &Bs[(wn * 64 + j * 16 + frow) * 32 + fk]);
#pragma unroll
        for (int i = 0; i < 4; ++i)
#pragma unroll
            for (int j = 0; j < 4; ++j)
                acc[i][j] = __builtin_amdgcn_mfma_f32_16x16x32_bf16(
                    af[i], bf[j], acc[i][j], 0, 0, 0);
        __syncthreads();
    }

    const int col = lane & 15;
    const int rq4 = (lane >> 4) << 2;
#pragma unroll
    for (int j = 0; j < 4; ++j) {
        const int n  = n0 + wn * 64 + j * 16 + col;
        const float bj = bias[n];
        const int h = n >> 6, d = n & 63;
        const size_t cbase = (size_t)h * (kS * kHD) + d;
#pragma unroll
        for (int i = 0; i < 4; ++i) {
            const int mrow = m0 + wm * 64 + i * 16 + rq4;
            const int bb = mrow >> 9;
            const int ss = mrow & 511;
            float* po = out + (size_t)bb * (kNH * kS * kHD) + cbase
                            + (size_t)ss * kHD;
#pragma unroll
            for (int r = 0; r < 4; ++r)
                po[(size_t)r * kHD] = acc[i][j][r] + bj;
        }
    }
}

// ---------------------------------------------------------------------------
// Fused attention, 32 q-rows per block.
// Unnormalized exp values stay in REGISTERS (ereg[8][2][4] = 64 VGPR,
// fully-unrolled kt loop for static indexing) until the full 512-key row sum
// is known; probs written ONCE, normalized, via nontemporal f32x4 stores.
// Removes the probs read-back + rewrite pass (~402 MB of 741 MB traffic).
// Row sums: 16-lane __shfl_xor butterfly.
// Grid: 3072 1D blocks with bijective XCD-chunk swizzle (384/XCD).
// ---------------------------------------------------------------------------
__global__ __launch_bounds__(256) void attn_kernel(
    const float* __restrict__ qo, const float* __restrict__ ko,
    const float* __restrict__ vo, const float* __restrict__ mask,
    float* __restrict__ ctx, float* __restrict__ probs)
{
    const int bid = blockIdx.x;
    const int swz = (bid & 7) * 384 + (bid >> 3);   // 3072 = 8 * 384, bijective
    const int qt  = swz & 15;
    const int rem = swz >> 4;
    const int h   = rem % kNH;
    const int b   = rem / kNH;
    const int bh  = b * kNH + h;
    const int q0  = qt * 32;

    const int t  = threadIdx.x;
    const int tx = t & 15;          // k-col group (4 cols)
    const int ty = t >> 4;          // q-row group (2 rows)

    __shared__ float Qt_s[64 * 34];   // [d][qrow] transposed (pad 34)
    __shared__ float KV  [64 * 68];   // K phase: [d][k]; V phase: [k][d]
    __shared__ float Pst [32 * 68];   // unnormalized probs tile (for PV)
    __shared__ float Madd[64];

    // ---- stage Q transposed: Qt_s[d][row] ----
    {
        const int qr = t >> 3;          // 0..31
        const int qc = (t & 7) * 8;     // 0..56
        const float* qrow = qo + ((size_t)(bh * kS + q0 + qr)) * kHD + qc;
        float4 v0 = *reinterpret_cast<const float4*>(qrow);
        float4 v1 = *reinterpret_cast<const float4*>(qrow + 4);
        Qt_s[(qc + 0) * 34 + qr] = v0.x;
        Qt_s[(qc + 1) * 34 + qr] = v0.y;
        Qt_s[(qc + 2) * 34 + qr] = v0.z;
        Qt_s[(qc + 3) * 34 + qr] = v0.w;
        Qt_s[(qc + 4) * 34 + qr] = v1.x;
        Qt_s[(qc + 5) * 34 + qr] = v1.y;
        Qt_s[(qc + 6) * 34 + qr] = v1.z;
        Qt_s[(qc + 7) * 34 + qr] = v1.w;
    }

    float ereg[8][2][4];            // 64 VGPR: unnormalized probs, whole row
    float cacc[2][4] = {};
    float rs0 = 0.0f, rs1 = 0.0f;
    const float scale = 0.125f;

    const int lr = t >> 2;          // 0..63 (K/V stage row)
    const int lc = (t & 3) * 16;    // 0..48

#pragma unroll
    for (int kt = 0; kt < 8; ++kt) {
        // stage K tile transposed: KV[d][k]
        {
            const float* krow = ko + ((size_t)(bh * kS + kt * 64 + lr)) * kHD + lc;
#pragma unroll
            for (int z4 = 0; z4 < 4; ++z4) {
                float4 v4 = *reinterpret_cast<const float4*>(krow + z4 * 4);
                KV[(lc + z4 * 4 + 0) * 68 + lr] = v4.x;
                KV[(lc + z4 * 4 + 1) * 68 + lr] = v4.y;
                KV[(lc + z4 * 4 + 2) * 68 + lr] = v4.z;
                KV[(lc + z4 * 4 + 3) * 68 + lr] = v4.w;
            }
        }
        if (t < 64) Madd[t] = (1.0f - mask[b * kS + kt * 64 + t]) * -10000.0f;
        __syncthreads();            // K + Madd ready (also guards Qt_s on kt=0)

        // QK^T: e[i][j] for rows ty*2+i, cols tx*4+j
        float e[2][4] = {};
#pragma unroll 4
        for (int d = 0; d < 64; ++d) {
            float2 a2 = *reinterpret_cast<const float2*>(&Qt_s[d * 34 + ty * 2]);
            float4 b4 = *reinterpret_cast<const float4*>(&KV[d * 68 + tx * 4]);
            e[0][0] = fmaf(a2.x, b4.x, e[0][0]);
            e[0][1] = fmaf(a2.x, b4.y, e[0][1]);
            e[0][2] = fmaf(a2.x, b4.z, e[0][2]);
            e[0][3] = fmaf(a2.x, b4.w, e[0][3]);
            e[1][0] = fmaf(a2.y, b4.x, e[1][0]);
            e[1][1] = fmaf(a2.y, b4.y, e[1][1]);
            e[1][2] = fmaf(a2.y, b4.z, e[1][2]);
            e[1][3] = fmaf(a2.y, b4.w, e[1][3]);
        }

        const float ma0 = Madd[tx * 4 + 0];
        const float ma1 = Madd[tx * 4 + 1];
        const float ma2 = Madd[tx * 4 + 2];
        const float ma3 = Madd[tx * 4 + 3];
#pragma unroll
        for (int i = 0; i < 2; ++i) {
            float p0 = __expf(fmaf(e[i][0], scale, ma0));
            float p1 = __expf(fmaf(e[i][1], scale, ma1));
            float p2 = __expf(fmaf(e[i][2], scale, ma2));
            float p3 = __expf(fmaf(e[i][3], scale, ma3));
            ereg[kt][i][0] = p0; ereg[kt][i][1] = p1;
            ereg[kt][i][2] = p2; ereg[kt][i][3] = p3;
            float s = (p0 + p1) + (p2 + p3);
            if (i == 0) rs0 += s; else rs1 += s;
            float4 pv; pv.x = p0; pv.y = p1; pv.z = p2; pv.w = p3;
            *reinterpret_cast<float4*>(&Pst[(ty * 2 + i) * 68 + tx * 4]) = pv;
        }
        __syncthreads();            // all done reading KV-as-K, Pst complete

        // stage V tile row-major into KV: KV[k][d]
        {
            const float* vrow = vo + ((size_t)(bh * kS + kt * 64 + lr)) * kHD + lc;
#pragma unroll
            for (int z4 = 0; z4 < 4; ++z4)
                *reinterpret_cast<float4*>(&KV[lr * 68 + lc + z4 * 4]) =
                    *reinterpret_cast<const float4*>(vrow + z4 * 4);
        }
        __syncthreads();            // V ready

        // PV: cacc[i][j] += sum_z Pst[row][z] * V[z][col]   (unnormalized)
#pragma unroll 2
        for (int kj0 = 0; kj0 < 64; kj0 += 4) {
            float4 p0 = *reinterpret_cast<const float4*>(&Pst[(ty * 2 + 0) * 68 + kj0]);
            float4 p1 = *reinterpret_cast<const float4*>(&Pst[(ty * 2 + 1) * 68 + kj0]);
            const float pr0[4] = {p0.x, p0.y, p0.z, p0.w};
            const float pr1[4] = {p1.x, p1.y, p1.z, p1.w};
#pragma unroll
            for (int z = 0; z < 4; ++z) {
                float4 v4 = *reinterpret_cast<const float4*>(&KV[(kj0 + z) * 68 + tx * 4]);
                cacc[0][0] = fmaf(pr0[z], v4.x, cacc[0][0]);
                cacc[0][1] = fmaf(pr0[z], v4.y, cacc[0][1]);
                cacc[0][2] = fmaf(pr0[z], v4.z, cacc[0][2]);
                cacc[0][3] = fmaf(pr0[z], v4.w, cacc[0][3]);
                cacc[1][0] = fmaf(pr1[z], v4.x, cacc[1][0]);
                cacc[1][1] = fmaf(pr1[z], v4.y, cacc[1][1]);
                cacc[1][2] = fmaf(pr1[z], v4.z, cacc[1][2]);
                cacc[1][3] = fmaf(pr1[z], v4.w, cacc[1][3]);
            }
        }
        __syncthreads();            // done with KV-as-V + Pst before next kt
    }

    // Row-sum butterfly over the 16 lanes owning each q-row pair
#pragma unroll
    for (int m = 8; m >= 1; m >>= 1) {
        rs0 += __shfl_xor(rs0, m, 64);
        rs1 += __shfl_xor(rs1, m, 64);
    }
    const float inv0 = 1.0f / rs0;
    const float inv1 = 1.0f / rs1;

    // Single normalized probs write (streaming, never re-read)
    {
        float* pr0 = probs + ((size_t)(bh * kS + q0 + ty * 2 + 0)) * kS + tx * 4;
        float* pr1 = pr0 + kS;
#pragma unroll
        for (int kt = 0; kt < 8; ++kt) {
            f32x4 o0, o1;
            o0.x = ereg[kt][0][0] * inv0; o0.y = ereg[kt][0][1] * inv0;
            o0.z = ereg[kt][0][2] * inv0; o0.w = ereg[kt][0][3] * inv0;
            o1.x = ereg[kt][1][0] * inv1; o1.y = ereg[kt][1][1] * inv1;
            o1.z = ereg[kt][1][2] * inv1; o1.w = ereg[kt][1][3] * inv1;
            __builtin_nontemporal_store(o0, reinterpret_cast<f32x4*>(pr0 + kt * 64));
            __builtin_nontemporal_store(o1, reinterpret_cast<f32x4*>(pr1 + kt * 64));
        }
    }

    // ctx write
#pragma unroll
    for (int i = 0; i < 2; ++i) {
        const float inv = i ? inv1 : inv0;
        f32x4 o;
        o.x = cacc[i][0] * inv; o.y = cacc[i][1] * inv;
        o.z = cacc[i][2] * inv; o.w = cacc[i][3] * inv;
        __builtin_nontemporal_store(o, reinterpret_cast<f32x4*>(
            ctx + ((size_t)(b * kS + q0 + ty * 2 + i)) * kH + h * kHD + tx * 4));
    }
}

extern "C" void kernel_launch(void* const* d_in, const int* in_sizes, int n_in,
                              void* d_out, int out_size, void* d_ws, size_t ws_size,
                              hipStream_t stream) {
    (void)in_sizes; (void)n_in; (void)out_size; (void)ws_size;

    const float* hidden = (const float*)d_in[0];
    const float* mask   = (const float*)d_in[1];
    const float* Wq     = (const float*)d_in[2];
    const float* bq     = (const float*)d_in[3];
    const float* Wk     = (const float*)d_in[4];
    const float* bk     = (const float*)d_in[5];
    const float* Wv     = (const float*)d_in[6];
    const float* bv     = (const float*)d_in[7];

    float* ctx   = (float*)d_out;
    float* probs = (float*)d_out + (size_t)kB * kS * kH;

    // ws layout: bf16 hidden + bf16 weights, then fp32 q/k/v ([b,h,s,d]).
    unsigned short* hbf = (unsigned short*)d_ws;
    unsigned short* wqb = hbf + (size_t)kM * kH;
    unsigned short* wkb = wqb + (size_t)kH * kH;
    unsigned short* wvb = wkb + (size_t)kH * kH;
    float* qo = (float*)(wvb + (size_t)kH * kH);
    float* ko = qo + (size_t)kB * kNH * kS * kHD;
    float* vo = ko + (size_t)kB * kNH * kS * kHD;

    const int nh4 = (kM * kH) / 4;        // 1572864
    const int nw4 = (kH * kH) / 4;        // 147456
    f32_to_bf16_kernel<<<nh4 / 256, 256, 0, stream>>>(hidden, hbf, nh4);
    f32_to_bf16_kernel<<<nw4 / 256, 256, 0, stream>>>(Wq, wqb, nw4);
    f32_to_bf16_kernel<<<nw4 / 256, 256, 0, stream>>>(Wk, wkb, nw4);
    f32_to_bf16_kernel<<<nw4 / 256, 256, 0, stream>>>(Wv, wvb, nw4);

    dim3 gp(kH / 128, kM / 128, 3);       // (6, 64, 3)
    qkv_mfma_kernel<<<gp, 256, 0, stream>>>(hbf, wqb, wkb, wvb,
                                            bq, bk, bv, qo, ko, vo);

    attn_kernel<<<dim3(kB * kNH * (kS / 32)), 256, 0, stream>>>(
        qo, ko, vo, mask, ctx, probs);
}

// Round 5
// 399.649 us; speedup vs baseline: 1.4074x; 1.2667x over previous
//
#include <hip/hip_runtime.h>

namespace {
constexpr int kB  = 16;
constexpr int kS  = 512;
constexpr int kH  = 768;
constexpr int kNH = 12;
constexpr int kHD = 64;
constexpr int kM  = kB * kS;   // 8192
}

typedef __attribute__((ext_vector_type(8))) short  short8;   // bf16x8 frag (4 VGPRs)
typedef __attribute__((ext_vector_type(4))) float  f32x4;    // MFMA acc / NT stores
typedef __attribute__((ext_vector_type(4))) unsigned short us4;
typedef __attribute__((ext_vector_type(2))) unsigned int   u32x2;

__device__ __forceinline__ unsigned short f2bf(float x) {
    unsigned u = __float_as_uint(x);
    return (unsigned short)((u + 0x7FFFu + ((u >> 16) & 1u)) >> 16);   // RNE
}

__device__ __forceinline__ unsigned pack_bf16(float lo, float hi) {
    return (unsigned)f2bf(lo) | ((unsigned)f2bf(hi) << 16);
}

__device__ __forceinline__ void load_lds16(const unsigned short* g, unsigned short* l) {
    __builtin_amdgcn_global_load_lds(
        (const __attribute__((address_space(1))) void*)g,
        (__attribute__((address_space(3))) void*)l,
        16, 0, 0);
}

// ---------------------------------------------------------------------------
// fp32 -> bf16 conversion (exact-sized launch; 4 elems/thr)
// ---------------------------------------------------------------------------
__global__ __launch_bounds__(256) void f32_to_bf16_kernel(
    const float* __restrict__ src, unsigned short* __restrict__ dst, int n4)
{
    int i = blockIdx.x * 256 + threadIdx.x;
    if (i >= n4) return;
    float4 v = reinterpret_cast<const float4*>(src)[i];
    us4 o;
    o.x = f2bf(v.x); o.y = f2bf(v.y); o.z = f2bf(v.z); o.w = f2bf(v.w);
    reinterpret_cast<us4*>(dst)[i] = o;
}

// ---------------------------------------------------------------------------
// QKV projection, bf16 MFMA (m97 structure). Epilogue emits:
//   q, k : hi/lo bf16 planes [b,h,s,d]  (hi + lo reconstructs fp32 to ~2^-17)
//   v    : single bf16, TRANSPOSED [b,h,d,s]  (PV B-operand natural rows)
// ---------------------------------------------------------------------------
__global__ __launch_bounds__(256) void qkv_mfma_kernel(
    const unsigned short* __restrict__ hbf,
    const unsigned short* __restrict__ Wqb,
    const unsigned short* __restrict__ Wkb,
    const unsigned short* __restrict__ Wvb,
    const float* __restrict__ bq, const float* __restrict__ bk,
    const float* __restrict__ bv,
    unsigned short* __restrict__ qhi, unsigned short* __restrict__ qlo,
    unsigned short* __restrict__ khi, unsigned short* __restrict__ klo,
    unsigned short* __restrict__ vt)
{
    const int which = blockIdx.z;
    const unsigned short* W = (which == 0) ? Wqb : (which == 1) ? Wkb : Wvb;
    const float* bias       = (which == 0) ? bq  : (which == 1) ? bk  : bv;

    const int n0 = blockIdx.x * 128;
    const int m0 = blockIdx.y * 128;

    const int t    = threadIdx.x;
    const int lane = t & 63;
    const int w    = t >> 6;        // wave 0..3
    const int wm   = w >> 1;
    const int wn   = w & 1;

    __shared__ unsigned short As[128 * 32];   // [m][k]
    __shared__ unsigned short Bs[128 * 32];   // [n][k]

    f32x4 acc[4][4] = {};

    const int srow  = w * 32 + (lane >> 2);
    const int skoff = (lane & 3) * 8;
    const unsigned short* gA0 = hbf + (size_t)(m0 + srow) * kH + skoff;
    const unsigned short* gA1 = gA0 + (size_t)16 * kH;
    const unsigned short* gB0 = W   + (size_t)(n0 + srow) * kH + skoff;
    const unsigned short* gB1 = gB0 + (size_t)16 * kH;
    unsigned short* lA0 = &As[(w * 32) * 32];
    unsigned short* lA1 = &As[(w * 32 + 16) * 32];
    unsigned short* lB0 = &Bs[(w * 32) * 32];
    unsigned short* lB1 = &Bs[(w * 32 + 16) * 32];

    const int frow = lane & 15;
    const int fk   = (lane >> 4) * 8;

    for (int k0 = 0; k0 < kH; k0 += 32) {
        load_lds16(gA0 + k0, lA0);
        load_lds16(gA1 + k0, lA1);
        load_lds16(gB0 + k0, lB0);
        load_lds16(gB1 + k0, lB1);
        __syncthreads();

        short8 af[4], bf[4];
#pragma unroll
        for (int i = 0; i < 4; ++i)
            af[i] = *reinterpret_cast<const short8*>(
                &As[(wm * 64 + i * 16 + frow) * 32 + fk]);
#pragma unroll
        for (int j = 0; j < 4; ++j)
            bf[j] = *reinterpret_cast<const short8*>(
                &Bs[(wn * 64 + j * 16 + frow) * 32 + fk]);
#pragma unroll
        for (int i = 0; i < 4; ++i)
#pragma unroll
            for (int j = 0; j < 4; ++j)
                acc[i][j] = __builtin_amdgcn_mfma_f32_16x16x32_bf16(
                    af[i], bf[j], acc[i][j], 0, 0, 0);
        __syncthreads();
    }

    const int col = lane & 15;
    const int rq4 = (lane >> 4) << 2;

    if (which < 2) {
        unsigned short* ohi = which ? khi : qhi;
        unsigned short* olo = which ? klo : qlo;
#pragma unroll
        for (int j = 0; j < 4; ++j) {
            const int n  = n0 + wn * 64 + j * 16 + col;
            const float bj = bias[n];
            const int hh = n >> 6, d = n & 63;
#pragma unroll
            for (int i = 0; i < 4; ++i) {
                const int mrow = m0 + wm * 64 + i * 16 + rq4;
                const int bb = mrow >> 9;
                const int ss = mrow & 511;
                const size_t base =
                    ((size_t)(bb * kNH + hh) * kS + ss) * kHD + d;
#pragma unroll
                for (int r = 0; r < 4; ++r) {
                    float x = acc[i][j][r] + bj;
                    unsigned short hi = f2bf(x);
                    float res = x - __uint_as_float((unsigned)hi << 16);
                    ohi[base + (size_t)r * kHD] = hi;
                    olo[base + (size_t)r * kHD] = f2bf(res);
                }
            }
        }
    } else {
#pragma unroll
        for (int j = 0; j < 4; ++j) {
            const int n  = n0 + wn * 64 + j * 16 + col;
            const float bj = bias[n];
            const int hh = n >> 6, d = n & 63;
#pragma unroll
            for (int i = 0; i < 4; ++i) {
                const int mrow = m0 + wm * 64 + i * 16 + rq4;
                const int bb = mrow >> 9;
                const int ss = mrow & 511;
                us4 o;
                o.x = f2bf(acc[i][j][0] + bj);
                o.y = f2bf(acc[i][j][1] + bj);
                o.z = f2bf(acc[i][j][2] + bj);
                o.w = f2bf(acc[i][j][3] + bj);
                *reinterpret_cast<us4*>(
                    &vt[((size_t)(bb * kNH + hh) * kHD + d) * kS + ss]) = o;
            }
        }
    }
}

// ---------------------------------------------------------------------------
// MFMA fused attention. 4 waves x 16 q-rows = 64 q-rows per block.
// Swapped QK^T (mfma(K,Q) -> S^T[k][q], q = lane&15 is lane-local) with
// bf16 hi/lo split of q,k (fp32-equivalent scores). PV in plain bf16 with
// V pre-transposed [d][s]. P packed bf16 (2/dword) kept in 64 VGPRs for the
// single normalized probs write; bounced per-wave through LDS for PV A-frags.
// K/VT staged via global_load_lds w=16 with XOR-swizzled SOURCE addresses
// (linear LDS dest; read side applies the same XOR -> low-conflict banks).
// ---------------------------------------------------------------------------
__global__ __launch_bounds__(256) void attn_kernel(
    const unsigned short* __restrict__ qhi, const unsigned short* __restrict__ qlo,
    const unsigned short* __restrict__ khi, const unsigned short* __restrict__ klo,
    const unsigned short* __restrict__ vtp, const float* __restrict__ mask,
    float* __restrict__ ctx, float* __restrict__ probs)
{
    const int bid = blockIdx.x;
    const int swz = (bid & 7) * 192 + (bid >> 3);   // 1536 = 8*192, bijective
    const int qt  = swz & 7;
    const int bh  = swz >> 3;
    const int b   = bh / kNH;
    const int h   = bh % kNH;
    const int q0  = qt * 64;

    const int t    = threadIdx.x;
    const int lane = t & 63;
    const int w    = t >> 6;        // wave 0..3
    const int g    = lane >> 4;     // 0..3
    const int fr   = lane & 15;

    __shared__ unsigned short Khs[4096];   // 64k x 64d bf16, src-swizzled
    __shared__ unsigned short Kls[4096];
    __shared__ unsigned short Vts[4096];   // 64d x 64s bf16, src-swizzled
    __shared__ unsigned int   Pp[4][576];  // per-wave packed P: [16q][36] dwords

    // ---- Q fragments: direct global loads (one-time) ----
    const int qrow = q0 + w * 16 + fr;
    const unsigned short* qh = qhi + ((size_t)bh * kS + qrow) * kHD + g * 8;
    const unsigned short* ql = qlo + ((size_t)bh * kS + qrow) * kHD + g * 8;
    const short8 qfh0 = *reinterpret_cast<const short8*>(qh);
    const short8 qfh1 = *reinterpret_cast<const short8*>(qh + 32);
    const short8 qfl0 = *reinterpret_cast<const short8*>(ql);
    const short8 qfl1 = *reinterpret_cast<const short8*>(ql + 32);

    // ---- staging: chunk c = (w*2+i)*64 + lane; src pre-swizzled ----
    const int c0 = (w * 2 + 0) * 64 + lane;
    const int c1 = (w * 2 + 1) * 64 + lane;
    const int r0 = c0 >> 3, r1 = c1 >> 3;
    const int s0b = ((c0 & 7) * 16) ^ ((r0 & 7) << 4);
    const int s1b = ((c1 & 7) * 16) ^ ((r1 & 7) << 4);
    const int ko0 = r0 * 128 + s0b,  ko1 = r1 * 128 + s1b;     // K tile: 128B rows
    const int vo0 = r0 * 1024 + s0b, vo1 = r1 * 1024 + s1b;    // VT: 1024B glob rows
    const char* kh_b = (const char*)(khi + (size_t)bh * kS * kHD);
    const char* kl_b = (const char*)(klo + (size_t)bh * kS * kHD);
    const char* vt_b = (const char*)(vtp + (size_t)bh * kHD * kS);
    unsigned short* ldsK0 = &Khs[(w * 2 + 0) * 512];
    unsigned short* ldsK1 = &Khs[(w * 2 + 1) * 512];
    unsigned short* ldsL0 = &Kls[(w * 2 + 0) * 512];
    unsigned short* ldsL1 = &Kls[(w * 2 + 1) * 512];
    unsigned short* ldsV0 = &Vts[(w * 2 + 0) * 512];
    unsigned short* ldsV1 = &Vts[(w * 2 + 1) * 512];

    unsigned pk[8][4][2];           // packed bf16 P, whole 512-k row (64 VGPR)
    f32x4 cacc[4] = {};             // ctx acc: 4 d-tiles
    float rs = 0.0f;
    const float* mrow = mask + b * kS;

#pragma unroll
    for (int kt = 0; kt < 8; ++kt) {
        load_lds16((const unsigned short*)(kh_b + kt * 8192 + ko0), ldsK0);
        load_lds16((const unsigned short*)(kh_b + kt * 8192 + ko1), ldsK1);
        load_lds16((const unsigned short*)(kl_b + kt * 8192 + ko0), ldsL0);
        load_lds16((const unsigned short*)(kl_b + kt * 8192 + ko1), ldsL1);
        load_lds16((const unsigned short*)(vt_b + kt * 128 + vo0), ldsV0);
        load_lds16((const unsigned short*)(vt_b + kt * 128 + vo1), ldsV1);
        __syncthreads();            // drains vmcnt(0): tiles ready

        // ---- QK^T (swapped): S^T[k][q], hi/lo split, then exp+pack ----
#pragma unroll
        for (int ks = 0; ks < 4; ++ks) {
            f32x4 sa = {};
#pragma unroll
            for (int d2 = 0; d2 < 2; ++d2) {
                const int kr  = ks * 16 + fr;
                const int off = kr * 128 + ((d2 * 64 + g * 16) ^ ((kr & 7) << 4));
                short8 ah = *reinterpret_cast<const short8*>((const char*)Khs + off);
                short8 al = *reinterpret_cast<const short8*>((const char*)Kls + off);
                const short8 qhf = d2 ? qfh1 : qfh0;
                const short8 qlf = d2 ? qfl1 : qfl0;
                sa = __builtin_amdgcn_mfma_f32_16x16x32_bf16(ah, qhf, sa, 0, 0, 0);
                sa = __builtin_amdgcn_mfma_f32_16x16x32_bf16(ah, qlf, sa, 0, 0, 0);
                sa = __builtin_amdgcn_mfma_f32_16x16x32_bf16(al, qhf, sa, 0, 0, 0);
            }
            const float4 mv = *reinterpret_cast<const float4*>(
                &mrow[kt * 64 + ks * 16 + g * 4]);
            float p0 = __expf(fmaf(sa[0], 0.125f, fmaf(mv.x, 1e4f, -1e4f)));
            float p1 = __expf(fmaf(sa[1], 0.125f, fmaf(mv.y, 1e4f, -1e4f)));
            float p2 = __expf(fmaf(sa[2], 0.125f, fmaf(mv.z, 1e4f, -1e4f)));
            float p3 = __expf(fmaf(sa[3], 0.125f, fmaf(mv.w, 1e4f, -1e4f)));
            rs += (p0 + p1) + (p2 + p3);
            const unsigned u0 = pack_bf16(p0, p1);
            const unsigned u1 = pack_bf16(p2, p3);
            pk[kt][ks][0] = u0;
            pk[kt][ks][1] = u1;
            *reinterpret_cast<u32x2*>(&Pp[w][fr * 36 + ks * 8 + g * 2]) =
                (u32x2){u0, u1};
        }

        // ---- PV: ctx[q][d] += P[q][k] * V[k][d]  (bf16, V^T rows from LDS) ----
#pragma unroll
        for (int kp = 0; kp < 2; ++kp) {
            short8 pa = *reinterpret_cast<const short8*>(
                &Pp[w][fr * 36 + kp * 16 + g * 4]);
#pragma unroll
            for (int dt = 0; dt < 4; ++dt) {
                const int vr  = dt * 16 + fr;
                const int off = vr * 128 + ((kp * 64 + g * 16) ^ ((vr & 7) << 4));
                short8 vb = *reinterpret_cast<const short8*>((const char*)Vts + off);
                cacc[dt] = __builtin_amdgcn_mfma_f32_16x16x32_bf16(
                    pa, vb, cacc[dt], 0, 0, 0);
            }
        }
        __syncthreads();            // all reads done before next stage
    }

    // ---- row sums (q = fr is lane-local; reduce over g groups) ----
    rs += __shfl_xor(rs, 16, 64);
    rs += __shfl_xor(rs, 32, 64);
    const float inv = 1.0f / rs;

    // ---- single normalized probs write (streaming) ----
    float* prow = probs + ((size_t)bh * kS + qrow) * kS;
#pragma unroll
    for (int kt = 0; kt < 8; ++kt)
#pragma unroll
        for (int ks = 0; ks < 4; ++ks) {
            const unsigned u0 = pk[kt][ks][0], u1 = pk[kt][ks][1];
            f32x4 o;
            o.x = __uint_as_float(u0 << 16) * inv;
            o.y = __uint_as_float(u0 & 0xFFFF0000u) * inv;
            o.z = __uint_as_float(u1 << 16) * inv;
            o.w = __uint_as_float(u1 & 0xFFFF0000u) * inv;
            __builtin_nontemporal_store(
                o, reinterpret_cast<f32x4*>(prow + kt * 64 + ks * 16 + g * 4));
        }

    // ---- ctx write: rows q = g*4+r need inv from lane (g*4+r) ----
    float invr[4];
#pragma unroll
    for (int r = 0; r < 4; ++r) invr[r] = __shfl(inv, g * 4 + r, 64);
    float* crow = ctx + ((size_t)(b * kS + q0 + w * 16 + g * 4)) * kH
                      + h * kHD + fr;
#pragma unroll
    for (int dt = 0; dt < 4; ++dt)
#pragma unroll
        for (int r = 0; r < 4; ++r)
            __builtin_nontemporal_store(cacc[dt][r] * invr[r],
                                        crow + (size_t)r * kH + dt * 16);
}

extern "C" void kernel_launch(void* const* d_in, const int* in_sizes, int n_in,
                              void* d_out, int out_size, void* d_ws, size_t ws_size,
                              hipStream_t stream) {
    (void)in_sizes; (void)n_in; (void)out_size; (void)ws_size;

    const float* hidden = (const float*)d_in[0];
    const float* mask   = (const float*)d_in[1];
    const float* Wq     = (const float*)d_in[2];
    const float* bq     = (const float*)d_in[3];
    const float* Wk     = (const float*)d_in[4];
    const float* bk     = (const float*)d_in[5];
    const float* Wv     = (const float*)d_in[6];
    const float* bv     = (const float*)d_in[7];

    float* ctx   = (float*)d_out;
    float* probs = (float*)d_out + (size_t)kB * kS * kH;

    // ws layout: bf16 hidden + bf16 weights, then bf16 q(hi,lo)/k(hi,lo)/vT.
    unsigned short* hbf = (unsigned short*)d_ws;
    unsigned short* wqb = hbf + (size_t)kM * kH;
    unsigned short* wkb = wqb + (size_t)kH * kH;
    unsigned short* wvb = wkb + (size_t)kH * kH;
    unsigned short* qhi = wvb + (size_t)kH * kH;
    const size_t nqkv = (size_t)kB * kNH * kS * kHD;   // 6291456
    unsigned short* qlo = qhi + nqkv;
    unsigned short* khi = qlo + nqkv;
    unsigned short* klo = khi + nqkv;
    unsigned short* vt  = klo + nqkv;

    const int nh4 = (kM * kH) / 4;        // 1572864
    const int nw4 = (kH * kH) / 4;        // 147456
    f32_to_bf16_kernel<<<nh4 / 256, 256, 0, stream>>>(hidden, hbf, nh4);
    f32_to_bf16_kernel<<<nw4 / 256, 256, 0, stream>>>(Wq, wqb, nw4);
    f32_to_bf16_kernel<<<nw4 / 256, 256, 0, stream>>>(Wk, wkb, nw4);
    f32_to_bf16_kernel<<<nw4 / 256, 256, 0, stream>>>(Wv, wvb, nw4);

    dim3 gp(kH / 128, kM / 128, 3);       // (6, 64, 3)
    qkv_mfma_kernel<<<gp, 256, 0, stream>>>(hbf, wqb, wkb, wvb,
                                            bq, bk, bv,
                                            qhi, qlo, khi, klo, vt);

    attn_kernel<<<dim3(kB * kNH * (kS / 64)), 256, 0, stream>>>(
        qhi, qlo, khi, klo, vt, mask, ctx, probs);
}

// Round 6
// 399.042 us; speedup vs baseline: 1.4095x; 1.0015x over previous
//
#include <hip/hip_runtime.h>

namespace {
constexpr int kB  = 16;
constexpr int kS  = 512;
constexpr int kH  = 768;
constexpr int kNH = 12;
constexpr int kHD = 64;
constexpr int kM  = kB * kS;   // 8192
}

typedef __attribute__((ext_vector_type(8))) short  short8;   // bf16x8 frag (4 VGPRs)
typedef __attribute__((ext_vector_type(4))) float  f32x4;    // MFMA acc / NT stores
typedef __attribute__((ext_vector_type(4))) unsigned short us4;
typedef __attribute__((ext_vector_type(2))) unsigned int   u32x2;

__device__ __forceinline__ unsigned short f2bf(float x) {
    unsigned u = __float_as_uint(x);
    return (unsigned short)((u + 0x7FFFu + ((u >> 16) & 1u)) >> 16);   // RNE
}

__device__ __forceinline__ unsigned pack_bf16(float lo, float hi) {
    return (unsigned)f2bf(lo) | ((unsigned)f2bf(hi) << 16);
}

__device__ __forceinline__ void load_lds16(const unsigned short* g, unsigned short* l) {
    __builtin_amdgcn_global_load_lds(
        (const __attribute__((address_space(1))) void*)g,
        (__attribute__((address_space(3))) void*)l,
        16, 0, 0);
}

// ---------------------------------------------------------------------------
// fp32 -> bf16 conversion (exact-sized launch; 4 elems/thr)
// ---------------------------------------------------------------------------
__global__ __launch_bounds__(256) void f32_to_bf16_kernel(
    const float* __restrict__ src, unsigned short* __restrict__ dst, int n4)
{
    int i = blockIdx.x * 256 + threadIdx.x;
    if (i >= n4) return;
    float4 v = reinterpret_cast<const float4*>(src)[i];
    us4 o;
    o.x = f2bf(v.x); o.y = f2bf(v.y); o.z = f2bf(v.z); o.w = f2bf(v.w);
    reinterpret_cast<us4*>(dst)[i] = o;
}

// ---------------------------------------------------------------------------
// QKV projection, bf16 MFMA (m97 structure).  (unchanged this round)
//   q, k : hi/lo bf16 planes [b,h,s,d]  (hi + lo reconstructs fp32 to ~2^-17)
//   v    : single bf16, TRANSPOSED [b,h,d,s]
// ---------------------------------------------------------------------------
__global__ __launch_bounds__(256) void qkv_mfma_kernel(
    const unsigned short* __restrict__ hbf,
    const unsigned short* __restrict__ Wqb,
    const unsigned short* __restrict__ Wkb,
    const unsigned short* __restrict__ Wvb,
    const float* __restrict__ bq, const float* __restrict__ bk,
    const float* __restrict__ bv,
    unsigned short* __restrict__ qhi, unsigned short* __restrict__ qlo,
    unsigned short* __restrict__ khi, unsigned short* __restrict__ klo,
    unsigned short* __restrict__ vt)
{
    const int which = blockIdx.z;
    const unsigned short* W = (which == 0) ? Wqb : (which == 1) ? Wkb : Wvb;
    const float* bias       = (which == 0) ? bq  : (which == 1) ? bk  : bv;

    const int n0 = blockIdx.x * 128;
    const int m0 = blockIdx.y * 128;

    const int t    = threadIdx.x;
    const int lane = t & 63;
    const int w    = t >> 6;        // wave 0..3
    const int wm   = w >> 1;
    const int wn   = w & 1;

    __shared__ unsigned short As[128 * 32];   // [m][k]
    __shared__ unsigned short Bs[128 * 32];   // [n][k]

    f32x4 acc[4][4] = {};

    const int srow  = w * 32 + (lane >> 2);
    const int skoff = (lane & 3) * 8;
    const unsigned short* gA0 = hbf + (size_t)(m0 + srow) * kH + skoff;
    const unsigned short* gA1 = gA0 + (size_t)16 * kH;
    const unsigned short* gB0 = W   + (size_t)(n0 + srow) * kH + skoff;
    const unsigned short* gB1 = gB0 + (size_t)16 * kH;
    unsigned short* lA0 = &As[(w * 32) * 32];
    unsigned short* lA1 = &As[(w * 32 + 16) * 32];
    unsigned short* lB0 = &Bs[(w * 32) * 32];
    unsigned short* lB1 = &Bs[(w * 32 + 16) * 32];

    const int frow = lane & 15;
    const int fk   = (lane >> 4) * 8;

    for (int k0 = 0; k0 < kH; k0 += 32) {
        load_lds16(gA0 + k0, lA0);
        load_lds16(gA1 + k0, lA1);
        load_lds16(gB0 + k0, lB0);
        load_lds16(gB1 + k0, lB1);
        __syncthreads();

        short8 af[4], bf[4];
#pragma unroll
        for (int i = 0; i < 4; ++i)
            af[i] = *reinterpret_cast<const short8*>(
                &As[(wm * 64 + i * 16 + frow) * 32 + fk]);
#pragma unroll
        for (int j = 0; j < 4; ++j)
            bf[j] = *reinterpret_cast<const short8*>(
                &Bs[(wn * 64 + j * 16 + frow) * 32 + fk]);
#pragma unroll
        for (int i = 0; i < 4; ++i)
#pragma unroll
            for (int j = 0; j < 4; ++j)
                acc[i][j] = __builtin_amdgcn_mfma_f32_16x16x32_bf16(
                    af[i], bf[j], acc[i][j], 0, 0, 0);
        __syncthreads();
    }

    const int col = lane & 15;
    const int rq4 = (lane >> 4) << 2;

    if (which < 2) {
        unsigned short* ohi = which ? khi : qhi;
        unsigned short* olo = which ? klo : qlo;
#pragma unroll
        for (int j = 0; j < 4; ++j) {
            const int n  = n0 + wn * 64 + j * 16 + col;
            const float bj = bias[n];
            const int hh = n >> 6, d = n & 63;
#pragma unroll
            for (int i = 0; i < 4; ++i) {
                const int mrow = m0 + wm * 64 + i * 16 + rq4;
                const int bb = mrow >> 9;
                const int ss = mrow & 511;
                const size_t base =
                    ((size_t)(bb * kNH + hh) * kS + ss) * kHD + d;
#pragma unroll
                for (int r = 0; r < 4; ++r) {
                    float x = acc[i][j][r] + bj;
                    unsigned short hi = f2bf(x);
                    float res = x - __uint_as_float((unsigned)hi << 16);
                    ohi[base + (size_t)r * kHD] = hi;
                    olo[base + (size_t)r * kHD] = f2bf(res);
                }
            }
        }
    } else {
#pragma unroll
        for (int j = 0; j < 4; ++j) {
            const int n  = n0 + wn * 64 + j * 16 + col;
            const float bj = bias[n];
            const int hh = n >> 6, d = n & 63;
#pragma unroll
            for (int i = 0; i < 4; ++i) {
                const int mrow = m0 + wm * 64 + i * 16 + rq4;
                const int bb = mrow >> 9;
                const int ss = mrow & 511;
                us4 o;
                o.x = f2bf(acc[i][j][0] + bj);
                o.y = f2bf(acc[i][j][1] + bj);
                o.z = f2bf(acc[i][j][2] + bj);
                o.w = f2bf(acc[i][j][3] + bj);
                *reinterpret_cast<us4*>(
                    &vt[((size_t)(bb * kNH + hh) * kHD + d) * kS + ss]) = o;
            }
        }
    }
}

// ---------------------------------------------------------------------------
// MFMA fused attention, now DOUBLE-BUFFERED (T3-lite minimum pipeline):
//   prologue stages tile 0; each kt issues stage(kt+1) into buf^1 BEFORE
//   compute(kt), then ONE __syncthreads per kt (its implicit vmcnt(0) drain
//   lands after the loads flew under the MFMA+exp work). Barriers/tile: 2->1.
//   Pp is wave-private (no barrier needed). s_setprio(1) wraps the compute
//   phase (T5: dbuf creates stage-vs-compute wave role diversity).
// LDS: 2x(Khs+Kls+Vts) 48 KB + Pp 9 KB = 58.4 KB -> 2 blocks/CU (accepted
// occupancy trade for single-barrier pipelining).
// ---------------------------------------------------------------------------
__global__ __launch_bounds__(256) void attn_kernel(
    const unsigned short* __restrict__ qhi, const unsigned short* __restrict__ qlo,
    const unsigned short* __restrict__ khi, const unsigned short* __restrict__ klo,
    const unsigned short* __restrict__ vtp, const float* __restrict__ mask,
    float* __restrict__ ctx, float* __restrict__ probs)
{
    const int bid = blockIdx.x;
    const int swz = (bid & 7) * 192 + (bid >> 3);   // 1536 = 8*192, bijective
    const int qt  = swz & 7;
    const int bh  = swz >> 3;
    const int b   = bh / kNH;
    const int h   = bh % kNH;
    const int q0  = qt * 64;

    const int t    = threadIdx.x;
    const int lane = t & 63;
    const int w    = t >> 6;        // wave 0..3
    const int g    = lane >> 4;     // 0..3
    const int fr   = lane & 15;

    __shared__ unsigned short Khs[2][4096];   // 64k x 64d bf16, src-swizzled
    __shared__ unsigned short Kls[2][4096];
    __shared__ unsigned short Vts[2][4096];   // 64d x 64s bf16, src-swizzled
    __shared__ unsigned int   Pp[4][576];     // per-wave packed P (wave-private)

    // ---- Q fragments: direct global loads (one-time) ----
    const int qrow = q0 + w * 16 + fr;
    const unsigned short* qh = qhi + ((size_t)bh * kS + qrow) * kHD + g * 8;
    const unsigned short* ql = qlo + ((size_t)bh * kS + qrow) * kHD + g * 8;
    const short8 qfh0 = *reinterpret_cast<const short8*>(qh);
    const short8 qfh1 = *reinterpret_cast<const short8*>(qh + 32);
    const short8 qfl0 = *reinterpret_cast<const short8*>(ql);
    const short8 qfl1 = *reinterpret_cast<const short8*>(ql + 32);

    // ---- staging: chunk c = (w*2+i)*64 + lane; src pre-swizzled ----
    const int c0 = (w * 2 + 0) * 64 + lane;
    const int c1 = (w * 2 + 1) * 64 + lane;
    const int r0 = c0 >> 3, r1 = c1 >> 3;
    const int s0b = ((c0 & 7) * 16) ^ ((r0 & 7) << 4);
    const int s1b = ((c1 & 7) * 16) ^ ((r1 & 7) << 4);
    const int ko0 = r0 * 128 + s0b,  ko1 = r1 * 128 + s1b;     // K tile: 128B rows
    const int vo0 = r0 * 1024 + s0b, vo1 = r1 * 1024 + s1b;    // VT: 1024B glob rows
    const char* kh_b = (const char*)(khi + (size_t)bh * kS * kHD);
    const char* kl_b = (const char*)(klo + (size_t)bh * kS * kHD);
    const char* vt_b = (const char*)(vtp + (size_t)bh * kHD * kS);
    const int l0 = (w * 2 + 0) * 512;
    const int l1 = (w * 2 + 1) * 512;

    unsigned pk[8][4][2];           // packed bf16 P, whole 512-k row (64 VGPR)
    f32x4 cacc[4] = {};             // ctx acc: 4 d-tiles
    float rs = 0.0f;
    const float* mrow = mask + b * kS;

    // ---- prologue: stage tile 0 into buffer 0 ----
    load_lds16((const unsigned short*)(kh_b + ko0), &Khs[0][l0]);
    load_lds16((const unsigned short*)(kh_b + ko1), &Khs[0][l1]);
    load_lds16((const unsigned short*)(kl_b + ko0), &Kls[0][l0]);
    load_lds16((const unsigned short*)(kl_b + ko1), &Kls[0][l1]);
    load_lds16((const unsigned short*)(vt_b + vo0), &Vts[0][l0]);
    load_lds16((const unsigned short*)(vt_b + vo1), &Vts[0][l1]);

#pragma unroll
    for (int kt = 0; kt < 8; ++kt) {
        const int cur = kt & 1;
        __syncthreads();            // drains vmcnt(0): buf[cur] staged; all
                                    // waves done reading buf[cur^1]

        if (kt < 7) {               // issue next-tile loads; fly under compute
            const int nxt = cur ^ 1;
            load_lds16((const unsigned short*)(kh_b + (kt + 1) * 8192 + ko0), &Khs[nxt][l0]);
            load_lds16((const unsigned short*)(kh_b + (kt + 1) * 8192 + ko1), &Khs[nxt][l1]);
            load_lds16((const unsigned short*)(kl_b + (kt + 1) * 8192 + ko0), &Kls[nxt][l0]);
            load_lds16((const unsigned short*)(kl_b + (kt + 1) * 8192 + ko1), &Kls[nxt][l1]);
            load_lds16((const unsigned short*)(vt_b + (kt + 1) * 128 + vo0), &Vts[nxt][l0]);
            load_lds16((const unsigned short*)(vt_b + (kt + 1) * 128 + vo1), &Vts[nxt][l1]);
        }

        __builtin_amdgcn_s_setprio(1);

        // ---- QK^T (swapped): S^T[k][q], hi/lo split, then exp+pack ----
#pragma unroll
        for (int ks = 0; ks < 4; ++ks) {
            f32x4 sa = {};
#pragma unroll
            for (int d2 = 0; d2 < 2; ++d2) {
                const int kr  = ks * 16 + fr;
                const int off = kr * 128 + ((d2 * 64 + g * 16) ^ ((kr & 7) << 4));
                short8 ah = *reinterpret_cast<const short8*>((const char*)Khs[cur] + off);
                short8 al = *reinterpret_cast<const short8*>((const char*)Kls[cur] + off);
                const short8 qhf = d2 ? qfh1 : qfh0;
                const short8 qlf = d2 ? qfl1 : qfl0;
                sa = __builtin_amdgcn_mfma_f32_16x16x32_bf16(ah, qhf, sa, 0, 0, 0);
                sa = __builtin_amdgcn_mfma_f32_16x16x32_bf16(ah, qlf, sa, 0, 0, 0);
                sa = __builtin_amdgcn_mfma_f32_16x16x32_bf16(al, qhf, sa, 0, 0, 0);
            }
            const float4 mv = *reinterpret_cast<const float4*>(
                &mrow[kt * 64 + ks * 16 + g * 4]);
            float p0 = __expf(fmaf(sa[0], 0.125f, fmaf(mv.x, 1e4f, -1e4f)));
            float p1 = __expf(fmaf(sa[1], 0.125f, fmaf(mv.y, 1e4f, -1e4f)));
            float p2 = __expf(fmaf(sa[2], 0.125f, fmaf(mv.z, 1e4f, -1e4f)));
            float p3 = __expf(fmaf(sa[3], 0.125f, fmaf(mv.w, 1e4f, -1e4f)));
            rs += (p0 + p1) + (p2 + p3);
            const unsigned u0 = pack_bf16(p0, p1);
            const unsigned u1 = pack_bf16(p2, p3);
            pk[kt][ks][0] = u0;
            pk[kt][ks][1] = u1;
            *reinterpret_cast<u32x2*>(&Pp[w][fr * 36 + ks * 8 + g * 2]) =
                (u32x2){u0, u1};
        }

        // ---- PV: ctx[q][d] += P[q][k] * V[k][d]  (wave-private Pp bounce) ----
#pragma unroll
        for (int kp = 0; kp < 2; ++kp) {
            short8 pa = *reinterpret_cast<const short8*>(
                &Pp[w][fr * 36 + kp * 16 + g * 4]);
#pragma unroll
            for (int dt = 0; dt < 4; ++dt) {
                const int vr  = dt * 16 + fr;
                const int off = vr * 128 + ((kp * 64 + g * 16) ^ ((vr & 7) << 4));
                short8 vb = *reinterpret_cast<const short8*>((const char*)Vts[cur] + off);
                cacc[dt] = __builtin_amdgcn_mfma_f32_16x16x32_bf16(
                    pa, vb, cacc[dt], 0, 0, 0);
            }
        }

        __builtin_amdgcn_s_setprio(0);
    }

    // ---- row sums (q = fr is lane-local; reduce over g groups) ----
    rs += __shfl_xor(rs, 16, 64);
    rs += __shfl_xor(rs, 32, 64);
    const float inv = 1.0f / rs;

    // ---- single normalized probs write (streaming) ----
    float* prow = probs + ((size_t)bh * kS + qrow) * kS;
#pragma unroll
    for (int kt = 0; kt < 8; ++kt)
#pragma unroll
        for (int ks = 0; ks < 4; ++ks) {
            const unsigned u0 = pk[kt][ks][0], u1 = pk[kt][ks][1];
            f32x4 o;
            o.x = __uint_as_float(u0 << 16) * inv;
            o.y = __uint_as_float(u0 & 0xFFFF0000u) * inv;
            o.z = __uint_as_float(u1 << 16) * inv;
            o.w = __uint_as_float(u1 & 0xFFFF0000u) * inv;
            __builtin_nontemporal_store(
                o, reinterpret_cast<f32x4*>(prow + kt * 64 + ks * 16 + g * 4));
        }

    // ---- ctx write: rows q = g*4+r need inv from lane (g*4+r) ----
    float invr[4];
#pragma unroll
    for (int r = 0; r < 4; ++r) invr[r] = __shfl(inv, g * 4 + r, 64);
    float* crow = ctx + ((size_t)(b * kS + q0 + w * 16 + g * 4)) * kH
                      + h * kHD + fr;
#pragma unroll
    for (int dt = 0; dt < 4; ++dt)
#pragma unroll
        for (int r = 0; r < 4; ++r)
            __builtin_nontemporal_store(cacc[dt][r] * invr[r],
                                        crow + (size_t)r * kH + dt * 16);
}

extern "C" void kernel_launch(void* const* d_in, const int* in_sizes, int n_in,
                              void* d_out, int out_size, void* d_ws, size_t ws_size,
                              hipStream_t stream) {
    (void)in_sizes; (void)n_in; (void)out_size; (void)ws_size;

    const float* hidden = (const float*)d_in[0];
    const float* mask   = (const float*)d_in[1];
    const float* Wq     = (const float*)d_in[2];
    const float* bq     = (const float*)d_in[3];
    const float* Wk     = (const float*)d_in[4];
    const float* bk     = (const float*)d_in[5];
    const float* Wv     = (const float*)d_in[6];
    const float* bv     = (const float*)d_in[7];

    float* ctx   = (float*)d_out;
    float* probs = (float*)d_out + (size_t)kB * kS * kH;

    // ws layout: bf16 hidden + bf16 weights, then bf16 q(hi,lo)/k(hi,lo)/vT.
    unsigned short* hbf = (unsigned short*)d_ws;
    unsigned short* wqb = hbf + (size_t)kM * kH;
    unsigned short* wkb = wqb + (size_t)kH * kH;
    unsigned short* wvb = wkb + (size_t)kH * kH;
    unsigned short* qhi = wvb + (size_t)kH * kH;
    const size_t nqkv = (size_t)kB * kNH * kS * kHD;   // 6291456
    unsigned short* qlo = qhi + nqkv;
    unsigned short* khi = qlo + nqkv;
    unsigned short* klo = khi + nqkv;
    unsigned short* vt  = klo + nqkv;

    const int nh4 = (kM * kH) / 4;        // 1572864
    const int nw4 = (kH * kH) / 4;        // 147456
    f32_to_bf16_kernel<<<nh4 / 256, 256, 0, stream>>>(hidden, hbf, nh4);
    f32_to_bf16_kernel<<<nw4 / 256, 256, 0, stream>>>(Wq, wqb, nw4);
    f32_to_bf16_kernel<<<nw4 / 256, 256, 0, stream>>>(Wk, wkb, nw4);
    f32_to_bf16_kernel<<<nw4 / 256, 256, 0, stream>>>(Wv, wvb, nw4);

    dim3 gp(kH / 128, kM / 128, 3);       // (6, 64, 3)
    qkv_mfma_kernel<<<gp, 256, 0, stream>>>(hbf, wqb, wkb, wvb,
                                            bq, bk, bv,
                                            qhi, qlo, khi, klo, vt);

    attn_kernel<<<dim3(kB * kNH * (kS / 64)), 256, 0, stream>>>(
        qhi, qlo, khi, klo, vt, mask, ctx, probs);
}

// Round 7
// 383.742 us; speedup vs baseline: 1.4657x; 1.0399x over previous
//
#include <hip/hip_runtime.h>

namespace {
constexpr int kB  = 16;
constexpr int kS  = 512;
constexpr int kH  = 768;
constexpr int kNH = 12;
constexpr int kHD = 64;
constexpr int kM  = kB * kS;   // 8192
}

typedef __attribute__((ext_vector_type(8))) short  short8;   // bf16x8 frag (4 VGPRs)
typedef __attribute__((ext_vector_type(4))) float  f32x4;    // MFMA acc / NT stores
typedef __attribute__((ext_vector_type(4))) unsigned short us4;
typedef __attribute__((ext_vector_type(2))) unsigned int   u32x2;

__device__ __forceinline__ unsigned short f2bf(float x) {
    unsigned u = __float_as_uint(x);
    return (unsigned short)((u + 0x7FFFu + ((u >> 16) & 1u)) >> 16);   // RNE
}

__device__ __forceinline__ unsigned pack_bf16(float lo, float hi) {
    return (unsigned)f2bf(lo) | ((unsigned)f2bf(hi) << 16);
}

__device__ __forceinline__ void load_lds16(const unsigned short* g, unsigned short* l) {
    __builtin_amdgcn_global_load_lds(
        (const __attribute__((address_space(1))) void*)g,
        (__attribute__((address_space(3))) void*)l,
        16, 0, 0);
}

// ---------------------------------------------------------------------------
// Fused fp32 -> bf16 conversion for hidden + Wq + Wk + Wv (one launch).
// Grid exactly covers nH4 + 3*nW4 float4 units.
// ---------------------------------------------------------------------------
__global__ __launch_bounds__(256) void cvt_all_kernel(
    const float* __restrict__ hidden, const float* __restrict__ Wq,
    const float* __restrict__ Wk, const float* __restrict__ Wv,
    unsigned short* __restrict__ hbf, unsigned short* __restrict__ wqb,
    unsigned short* __restrict__ wkb, unsigned short* __restrict__ wvb)
{
    const int nH4 = (kM * kH) / 4;        // 1572864
    const int nW4 = (kH * kH) / 4;        // 147456
    int i = blockIdx.x * 256 + threadIdx.x;
    const float* src;
    unsigned short* dst;
    int off;
    if (i < nH4) {
        src = hidden; dst = hbf; off = i;
    } else {
        int j = i - nH4;
        int which = j / nW4;              // 0..2 (const divide -> magic mul)
        off = j - which * nW4;
        src = (which == 0) ? Wq : (which == 1) ? Wk : Wv;
        dst = (which == 0) ? wqb : (which == 1) ? wkb : wvb;
    }
    float4 v = reinterpret_cast<const float4*>(src)[off];
    us4 o;
    o.x = f2bf(v.x); o.y = f2bf(v.y); o.z = f2bf(v.z); o.w = f2bf(v.w);
    reinterpret_cast<us4*>(dst)[off] = o;
}

// ---------------------------------------------------------------------------
// QKV projection, bf16 MFMA. This round: BK=64 (12 k-iters, half the
// vmcnt(0)+barrier drains) + XOR-swizzled LDS tiles (rule #21: linear LDS
// dest via global_load_lds, involutive XOR applied to SOURCE and to READ;
// fixes the ~8-way bank conflict of 64/128-B-row fragment reads).
// Accumulation order identical to BK=32 version -> bit-identical output.
// Epilogue emits q,k hi/lo bf16 planes [b,h,s,d]; v bf16 transposed [b,h,d,s].
// ---------------------------------------------------------------------------
__global__ __launch_bounds__(256) void qkv_mfma_kernel(
    const unsigned short* __restrict__ hbf,
    const unsigned short* __restrict__ Wqb,
    const unsigned short* __restrict__ Wkb,
    const unsigned short* __restrict__ Wvb,
    const float* __restrict__ bq, const float* __restrict__ bk,
    const float* __restrict__ bv,
    unsigned short* __restrict__ qhi, unsigned short* __restrict__ qlo,
    unsigned short* __restrict__ khi, unsigned short* __restrict__ klo,
    unsigned short* __restrict__ vt)
{
    const int which = blockIdx.z;
    const unsigned short* W = (which == 0) ? Wqb : (which == 1) ? Wkb : Wvb;
    const float* bias       = (which == 0) ? bq  : (which == 1) ? bk  : bv;

    const int n0 = blockIdx.x * 128;
    const int m0 = blockIdx.y * 128;

    const int t    = threadIdx.x;
    const int lane = t & 63;
    const int w    = t >> 6;        // wave 0..3
    const int wm   = w >> 1;
    const int wn   = w & 1;

    __shared__ unsigned short As[128 * 64];   // [m][k64], 128 B rows, swizzled
    __shared__ unsigned short Bs[128 * 64];   // [n][k64]

    f32x4 acc[4][4] = {};

    // Staging: inst i covers rows w*32+8i .. +8i+7; lane -> (row8, unit).
    // Source pre-swizzled: unit_read = (lane&7) ^ row8, so LDS[r][u] holds
    // global[r][u ^ (r&7)] with a LINEAR LDS destination.
    const int row8  = lane >> 3;              // 0..7 (== row & 7)
    const int sunit = (lane & 7) ^ row8;      // swizzled 16B unit
    const unsigned short* gA = hbf + (size_t)(m0 + w * 32 + row8) * kH + sunit * 8;
    const unsigned short* gB = W   + (size_t)(n0 + w * 32 + row8) * kH + sunit * 8;

    const int frow = lane & 15;
    const int fk   = (lane >> 4) * 8;         // 0,8,16,24
    const int fswz = (frow & 7) << 3;         // element XOR for swizzled read

    for (int k0 = 0; k0 < kH; k0 += 64) {
#pragma unroll
        for (int i = 0; i < 4; ++i) {
            load_lds16(gA + k0 + (size_t)(8 * i) * kH, &As[(w * 32 + 8 * i) * 64]);
            load_lds16(gB + k0 + (size_t)(8 * i) * kH, &Bs[(w * 32 + 8 * i) * 64]);
        }
        __syncthreads();            // drains vmcnt(0): LDS tiles ready

        short8 af[2][4], bf[2][4];
#pragma unroll
        for (int kk = 0; kk < 2; ++kk) {
#pragma unroll
            for (int i = 0; i < 4; ++i)
                af[kk][i] = *reinterpret_cast<const short8*>(
                    &As[(wm * 64 + i * 16 + frow) * 64 + ((kk * 32 + fk) ^ fswz)]);
#pragma unroll
            for (int j = 0; j < 4; ++j)
                bf[kk][j] = *reinterpret_cast<const short8*>(
                    &Bs[(wn * 64 + j * 16 + frow) * 64 + ((kk * 32 + fk) ^ fswz)]);
        }
#pragma unroll
        for (int kk = 0; kk < 2; ++kk)
#pragma unroll
            for (int i = 0; i < 4; ++i)
#pragma unroll
                for (int j = 0; j < 4; ++j)
                    acc[i][j] = __builtin_amdgcn_mfma_f32_16x16x32_bf16(
                        af[kk][i], bf[kk][j], acc[i][j], 0, 0, 0);
        __syncthreads();
    }

    const int col = lane & 15;
    const int rq4 = (lane >> 4) << 2;

    if (which < 2) {
        unsigned short* ohi = which ? khi : qhi;
        unsigned short* olo = which ? klo : qlo;
#pragma unroll
        for (int j = 0; j < 4; ++j) {
            const int n  = n0 + wn * 64 + j * 16 + col;
            const float bj = bias[n];
            const int hh = n >> 6, d = n & 63;
#pragma unroll
            for (int i = 0; i < 4; ++i) {
                const int mrow = m0 + wm * 64 + i * 16 + rq4;
                const int bb = mrow >> 9;
                const int ss = mrow & 511;
                const size_t base =
                    ((size_t)(bb * kNH + hh) * kS + ss) * kHD + d;
#pragma unroll
                for (int r = 0; r < 4; ++r) {
                    float x = acc[i][j][r] + bj;
                    unsigned short hi = f2bf(x);
                    float res = x - __uint_as_float((unsigned)hi << 16);
                    ohi[base + (size_t)r * kHD] = hi;
                    olo[base + (size_t)r * kHD] = f2bf(res);
                }
            }
        }
    } else {
#pragma unroll
        for (int j = 0; j < 4; ++j) {
            const int n  = n0 + wn * 64 + j * 16 + col;
            const float bj = bias[n];
            const int hh = n >> 6, d = n & 63;
#pragma unroll
            for (int i = 0; i < 4; ++i) {
                const int mrow = m0 + wm * 64 + i * 16 + rq4;
                const int bb = mrow >> 9;
                const int ss = mrow & 511;
                us4 o;
                o.x = f2bf(acc[i][j][0] + bj);
                o.y = f2bf(acc[i][j][1] + bj);
                o.z = f2bf(acc[i][j][2] + bj);
                o.w = f2bf(acc[i][j][3] + bj);
                *reinterpret_cast<us4*>(
                    &vt[((size_t)(bb * kNH + hh) * kHD + d) * kS + ss]) = o;
            }
        }
    }
}

// ---------------------------------------------------------------------------
// MFMA fused attention (unchanged from R6: double-buffered, 1 barrier/kt,
// setprio around compute; swapped QK^T with hi/lo split; bf16 PV with V^T;
// probs written once, normalized, NT f32x4).
// ---------------------------------------------------------------------------
__global__ __launch_bounds__(256) void attn_kernel(
    const unsigned short* __restrict__ qhi, const unsigned short* __restrict__ qlo,
    const unsigned short* __restrict__ khi, const unsigned short* __restrict__ klo,
    const unsigned short* __restrict__ vtp, const float* __restrict__ mask,
    float* __restrict__ ctx, float* __restrict__ probs)
{
    const int bid = blockIdx.x;
    const int swz = (bid & 7) * 192 + (bid >> 3);   // 1536 = 8*192, bijective
    const int qt  = swz & 7;
    const int bh  = swz >> 3;
    const int b   = bh / kNH;
    const int h   = bh % kNH;
    const int q0  = qt * 64;

    const int t    = threadIdx.x;
    const int lane = t & 63;
    const int w    = t >> 6;        // wave 0..3
    const int g    = lane >> 4;     // 0..3
    const int fr   = lane & 15;

    __shared__ unsigned short Khs[2][4096];   // 64k x 64d bf16, src-swizzled
    __shared__ unsigned short Kls[2][4096];
    __shared__ unsigned short Vts[2][4096];   // 64d x 64s bf16, src-swizzled
    __shared__ unsigned int   Pp[4][576];     // per-wave packed P (wave-private)

    // ---- Q fragments: direct global loads (one-time) ----
    const int qrow = q0 + w * 16 + fr;
    const unsigned short* qh = qhi + ((size_t)bh * kS + qrow) * kHD + g * 8;
    const unsigned short* ql = qlo + ((size_t)bh * kS + qrow) * kHD + g * 8;
    const short8 qfh0 = *reinterpret_cast<const short8*>(qh);
    const short8 qfh1 = *reinterpret_cast<const short8*>(qh + 32);
    const short8 qfl0 = *reinterpret_cast<const short8*>(ql);
    const short8 qfl1 = *reinterpret_cast<const short8*>(ql + 32);

    // ---- staging: chunk c = (w*2+i)*64 + lane; src pre-swizzled ----
    const int c0 = (w * 2 + 0) * 64 + lane;
    const int c1 = (w * 2 + 1) * 64 + lane;
    const int r0 = c0 >> 3, r1 = c1 >> 3;
    const int s0b = ((c0 & 7) * 16) ^ ((r0 & 7) << 4);
    const int s1b = ((c1 & 7) * 16) ^ ((r1 & 7) << 4);
    const int ko0 = r0 * 128 + s0b,  ko1 = r1 * 128 + s1b;     // K tile: 128B rows
    const int vo0 = r0 * 1024 + s0b, vo1 = r1 * 1024 + s1b;    // VT: 1024B glob rows
    const char* kh_b = (const char*)(khi + (size_t)bh * kS * kHD);
    const char* kl_b = (const char*)(klo + (size_t)bh * kS * kHD);
    const char* vt_b = (const char*)(vtp + (size_t)bh * kHD * kS);
    const int l0 = (w * 2 + 0) * 512;
    const int l1 = (w * 2 + 1) * 512;

    unsigned pk[8][4][2];           // packed bf16 P, whole 512-k row (64 VGPR)
    f32x4 cacc[4] = {};             // ctx acc: 4 d-tiles
    float rs = 0.0f;
    const float* mrow = mask + b * kS;

    // ---- prologue: stage tile 0 into buffer 0 ----
    load_lds16((const unsigned short*)(kh_b + ko0), &Khs[0][l0]);
    load_lds16((const unsigned short*)(kh_b + ko1), &Khs[0][l1]);
    load_lds16((const unsigned short*)(kl_b + ko0), &Kls[0][l0]);
    load_lds16((const unsigned short*)(kl_b + ko1), &Kls[0][l1]);
    load_lds16((const unsigned short*)(vt_b + vo0), &Vts[0][l0]);
    load_lds16((const unsigned short*)(vt_b + vo1), &Vts[0][l1]);

#pragma unroll
    for (int kt = 0; kt < 8; ++kt) {
        const int cur = kt & 1;
        __syncthreads();            // drains vmcnt(0): buf[cur] staged; all
                                    // waves done reading buf[cur^1]

        if (kt < 7) {               // issue next-tile loads; fly under compute
            const int nxt = cur ^ 1;
            load_lds16((const unsigned short*)(kh_b + (kt + 1) * 8192 + ko0), &Khs[nxt][l0]);
            load_lds16((const unsigned short*)(kh_b + (kt + 1) * 8192 + ko1), &Khs[nxt][l1]);
            load_lds16((const unsigned short*)(kl_b + (kt + 1) * 8192 + ko0), &Kls[nxt][l0]);
            load_lds16((const unsigned short*)(kl_b + (kt + 1) * 8192 + ko1), &Kls[nxt][l1]);
            load_lds16((const unsigned short*)(vt_b + (kt + 1) * 128 + vo0), &Vts[nxt][l0]);
            load_lds16((const unsigned short*)(vt_b + (kt + 1) * 128 + vo1), &Vts[nxt][l1]);
        }

        __builtin_amdgcn_s_setprio(1);

        // ---- QK^T (swapped): S^T[k][q], hi/lo split, then exp+pack ----
#pragma unroll
        for (int ks = 0; ks < 4; ++ks) {
            f32x4 sa = {};
#pragma unroll
            for (int d2 = 0; d2 < 2; ++d2) {
                const int kr  = ks * 16 + fr;
                const int off = kr * 128 + ((d2 * 64 + g * 16) ^ ((kr & 7) << 4));
                short8 ah = *reinterpret_cast<const short8*>((const char*)Khs[cur] + off);
                short8 al = *reinterpret_cast<const short8*>((const char*)Kls[cur] + off);
                const short8 qhf = d2 ? qfh1 : qfh0;
                const short8 qlf = d2 ? qfl1 : qfl0;
                sa = __builtin_amdgcn_mfma_f32_16x16x32_bf16(ah, qhf, sa, 0, 0, 0);
                sa = __builtin_amdgcn_mfma_f32_16x16x32_bf16(ah, qlf, sa, 0, 0, 0);
                sa = __builtin_amdgcn_mfma_f32_16x16x32_bf16(al, qhf, sa, 0, 0, 0);
            }
            const float4 mv = *reinterpret_cast<const float4*>(
                &mrow[kt * 64 + ks * 16 + g * 4]);
            float p0 = __expf(fmaf(sa[0], 0.125f, fmaf(mv.x, 1e4f, -1e4f)));
            float p1 = __expf(fmaf(sa[1], 0.125f, fmaf(mv.y, 1e4f, -1e4f)));
            float p2 = __expf(fmaf(sa[2], 0.125f, fmaf(mv.z, 1e4f, -1e4f)));
            float p3 = __expf(fmaf(sa[3], 0.125f, fmaf(mv.w, 1e4f, -1e4f)));
            rs += (p0 + p1) + (p2 + p3);
            const unsigned u0 = pack_bf16(p0, p1);
            const unsigned u1 = pack_bf16(p2, p3);
            pk[kt][ks][0] = u0;
            pk[kt][ks][1] = u1;
            *reinterpret_cast<u32x2*>(&Pp[w][fr * 36 + ks * 8 + g * 2]) =
                (u32x2){u0, u1};
        }

        // ---- PV: ctx[q][d] += P[q][k] * V[k][d]  (wave-private Pp bounce) ----
#pragma unroll
        for (int kp = 0; kp < 2; ++kp) {
            short8 pa = *reinterpret_cast<const short8*>(
                &Pp[w][fr * 36 + kp * 16 + g * 4]);
#pragma unroll
            for (int dt = 0; dt < 4; ++dt) {
                const int vr  = dt * 16 + fr;
                const int off = vr * 128 + ((kp * 64 + g * 16) ^ ((vr & 7) << 4));
                short8 vb = *reinterpret_cast<const short8*>((const char*)Vts[cur] + off);
                cacc[dt] = __builtin_amdgcn_mfma_f32_16x16x32_bf16(
                    pa, vb, cacc[dt], 0, 0, 0);
            }
        }

        __builtin_amdgcn_s_setprio(0);
    }

    // ---- row sums (q = fr is lane-local; reduce over g groups) ----
    rs += __shfl_xor(rs, 16, 64);
    rs += __shfl_xor(rs, 32, 64);
    const float inv = 1.0f / rs;

    // ---- single normalized probs write (streaming) ----
    float* prow = probs + ((size_t)bh * kS + qrow) * kS;
#pragma unroll
    for (int kt = 0; kt < 8; ++kt)
#pragma unroll
        for (int ks = 0; ks < 4; ++ks) {
            const unsigned u0 = pk[kt][ks][0], u1 = pk[kt][ks][1];
            f32x4 o;
            o.x = __uint_as_float(u0 << 16) * inv;
            o.y = __uint_as_float(u0 & 0xFFFF0000u) * inv;
            o.z = __uint_as_float(u1 << 16) * inv;
            o.w = __uint_as_float(u1 & 0xFFFF0000u) * inv;
            __builtin_nontemporal_store(
                o, reinterpret_cast<f32x4*>(prow + kt * 64 + ks * 16 + g * 4));
        }

    // ---- ctx write: rows q = g*4+r need inv from lane (g*4+r) ----
    float invr[4];
#pragma unroll
    for (int r = 0; r < 4; ++r) invr[r] = __shfl(inv, g * 4 + r, 64);
    float* crow = ctx + ((size_t)(b * kS + q0 + w * 16 + g * 4)) * kH
                      + h * kHD + fr;
#pragma unroll
    for (int dt = 0; dt < 4; ++dt)
#pragma unroll
        for (int r = 0; r < 4; ++r)
            __builtin_nontemporal_store(cacc[dt][r] * invr[r],
                                        crow + (size_t)r * kH + dt * 16);
}

extern "C" void kernel_launch(void* const* d_in, const int* in_sizes, int n_in,
                              void* d_out, int out_size, void* d_ws, size_t ws_size,
                              hipStream_t stream) {
    (void)in_sizes; (void)n_in; (void)out_size; (void)ws_size;

    const float* hidden = (const float*)d_in[0];
    const float* mask   = (const float*)d_in[1];
    const float* Wq     = (const float*)d_in[2];
    const float* bq     = (const float*)d_in[3];
    const float* Wk     = (const float*)d_in[4];
    const float* bk     = (const float*)d_in[5];
    const float* Wv     = (const float*)d_in[6];
    const float* bv     = (const float*)d_in[7];

    float* ctx   = (float*)d_out;
    float* probs = (float*)d_out + (size_t)kB * kS * kH;

    // ws layout: bf16 hidden + bf16 weights, then bf16 q(hi,lo)/k(hi,lo)/vT.
    unsigned short* hbf = (unsigned short*)d_ws;
    unsigned short* wqb = hbf + (size_t)kM * kH;
    unsigned short* wkb = wqb + (size_t)kH * kH;
    unsigned short* wvb = wkb + (size_t)kH * kH;
    unsigned short* qhi = wvb + (size_t)kH * kH;
    const size_t nqkv = (size_t)kB * kNH * kS * kHD;   // 6291456
    unsigned short* qlo = qhi + nqkv;
    unsigned short* khi = qlo + nqkv;
    unsigned short* klo = khi + nqkv;
    unsigned short* vt  = klo + nqkv;

    // One fused convert launch: (nH4 + 3*nW4)/256 = 7872 blocks exactly.
    const int ncvt = ((kM * kH) / 4 + 3 * (kH * kH) / 4) / 256;
    cvt_all_kernel<<<ncvt, 256, 0, stream>>>(hidden, Wq, Wk, Wv,
                                             hbf, wqb, wkb, wvb);

    dim3 gp(kH / 128, kM / 128, 3);       // (6, 64, 3)
    qkv_mfma_kernel<<<gp, 256, 0, stream>>>(hbf, wqb, wkb, wvb,
                                            bq, bk, bv,
                                            qhi, qlo, khi, klo, vt);

    attn_kernel<<<dim3(kB * kNH * (kS / 64)), 256, 0, stream>>>(
        qhi, qlo, khi, klo, vt, mask, ctx, probs);
}